// Round 5
// baseline (364.243 us; speedup 1.0000x reference)
//
#include <hip/hip_runtime.h>
#include <hip/hip_fp16.h>

#define PCELLS (16*16*16*16*16)   // 1048576
#define CCH 32

typedef float f32x4 __attribute__((ext_vector_type(4)));
// 4-B-aligned float4 (ray rows are 20 B apart; CDNA supports unaligned VMEM)
typedef float f32x4u __attribute__((ext_vector_type(4), aligned(4)));

// xor-4 lane butterfly via ds_swizzle (BitMode: xor=4, and=0x1F -> 0x101F)
__device__ __forceinline__ float swz_xor4(float x) {
    return __int_as_float(__builtin_amdgcn_ds_swizzle(__float_as_int(x), 0x101F));
}

__device__ __forceinline__ unsigned pack2(float a, float b) {
    __half2 h = __floats2half2_rn(a, b);
    return *(unsigned*)&h;
}

// ---------------------------------------------------------------------------
// K1 v3: (C=32, P) f32 -> permuted (cell, C=32) f16, cell = r*256 + d01,
// with p = d01*4096 + r. Tile: 16 r x 32 d01 x 32 c.
//   Load : 1024 rows (c, d01) of 16 consecutive floats (one 64-B line each;
//          every grid line read exactly once, no amplification).
//   Store: 32 KB per block as wave-level 1-KB contiguous nontemporal stores
//          (fully streaming writes -- was scattered 128-B @ 16-KB stride).
// LDS: uint2 hq[c][j][5] = rows of 20 halves (i-dim padded 16->20) so b64
// writes stay 8-B aligned; worst bank conflict 4-way on 4 instrs (cheap).
// ---------------------------------------------------------------------------
__global__ __launch_bounds__(256) void transpose_kernel(
        const float* __restrict__ g, __half* __restrict__ gt) {
    __shared__ uint2 hq[32][32][5];     // [c][j][i2], 40 KB
    const int bx = blockIdx.x;
    const int db = bx >> 8;             // d01 tile 0..7  (32 d01 each)
    const int rt = bx & 255;            // r   tile 0..255 (16 r each)
    const int t  = threadIdx.x;
    const int j  = t & 31;              // d01 within tile

    // ---- load + convert: rows (c, j) of 16 floats -------------------------
#pragma unroll
    for (int rr = 0; rr < 4; ++rr) {
        int c = (t >> 5) + 8 * rr;
        const float* src = g + (size_t)c * PCELLS
                             + (size_t)(db * 32 + j) * 4096 + (size_t)rt * 16;
        f32x4 v0 = __builtin_nontemporal_load((const f32x4*)(src));
        f32x4 v1 = __builtin_nontemporal_load((const f32x4*)(src + 4));
        f32x4 v2 = __builtin_nontemporal_load((const f32x4*)(src + 8));
        f32x4 v3 = __builtin_nontemporal_load((const f32x4*)(src + 12));
        uint2 u0, u1, u2, u3;
        u0.x = pack2(v0[0], v0[1]);  u0.y = pack2(v0[2], v0[3]);
        u1.x = pack2(v1[0], v1[1]);  u1.y = pack2(v1[2], v1[3]);
        u2.x = pack2(v2[0], v2[1]);  u2.y = pack2(v2[2], v2[3]);
        u3.x = pack2(v3[0], v3[1]);  u3.y = pack2(v3[2], v3[3]);
        hq[c][j][0] = u0;  hq[c][j][1] = u1;
        hq[c][j][2] = u2;  hq[c][j][3] = u3;
    }
    __syncthreads();

    // ---- store: 2048 units of 16 B, wave-coalesced 1-KB rows --------------
    const __half* hl = (const __half*)&hq[0][0][0];
#pragma unroll
    for (int m = 0; m < 8; ++m) {
        int flat = t + 256 * m;         // 0..2047
        int i  = flat >> 7;             // r within tile 0..15
        int u  = flat & 127;            // 16-B unit within 2-KB r-row
        int jj = u >> 2;                // d01 within tile
        int o  = u & 3;                 // channel octet
        unsigned d[4];
#pragma unroll
        for (int dd = 0; dd < 4; ++dd) {
            __half a = hl[((8 * o + 2 * dd)     * 32 + jj) * 20 + i];
            __half b = hl[((8 * o + 2 * dd + 1) * 32 + jj) * 20 + i];
            __half2 hh = __halves2half2(a, b);
            d[dd] = *(unsigned*)&hh;
        }
        size_t byte = (size_t)rt * 262144 + (size_t)db * 2048
                    + (size_t)i * 16384 + (size_t)u * 16;
        __builtin_nontemporal_store(*(f32x4*)d, (f32x4*)((char*)gt + byte));
    }
}

// ---------------------------------------------------------------------------
// K2: fused prep+gather (unchanged from round 4: 8 lanes/ray, 2 rays/thread,
// wave = 16 rays). Per ray TWO scattered 128-B spans (corner pairs (l,l+1),
// (l+16,l+17)); lane j covers bytes 16j -> cell l+(j>>2), channel octet j&3.
// d1-corner pair combined with one xor-4 butterfly per accumulator float.
// ---------------------------------------------------------------------------
__global__ __launch_bounds__(256) void fused_gather(
        const float* __restrict__ ray, const __half* __restrict__ gt,
        const float* __restrict__ mn, const float* __restrict__ mx,
        float* __restrict__ out, int N) {
    int tid  = blockIdx.x * blockDim.x + threadIdx.x;
    int lane = tid & 63;
    int wv   = tid >> 6;          // global wave id
    int gi   = lane >> 3;         // group within wave (8 lanes/group)
    int j    = lane & 7;          // lane within group
    int n0   = wv * 16 + gi;      // wave handles rays [16w, 16w+16)
    if (n0 >= N) return;          // group-uniform exit
    int  n1   = n0 + 8;
    bool has1 = n1 < N;
    int  n1c  = has1 ? n1 : n0;

    // --- vectorized ray loads ---------------------------------------------
    const float* rp0 = ray + (size_t)n0  * 5;
    const float* rp1 = ray + (size_t)n1c * 5;
    float rv0[5], rv1[5];
    *(f32x4u*)rv0 = *(const f32x4u*)rp0;  rv0[4] = rp0[4];
    *(f32x4u*)rv1 = *(const f32x4u*)rp1;  rv1[4] = rp1[4];

    // --- corner base + weights --------------------------------------------
    float wa[5], wb[5]; int ba[5], bb[5];
#pragma unroll
    for (int d = 0; d < 5; ++d) {
        float m   = mn[d];
        float inv = __builtin_amdgcn_rcpf(mx[d] - m) * 15.0f;
        float i0  = (rv0[d] - m) * inv;
        float i1  = (rv1[d] - m) * inv;
        float f0 = floorf(i0), f1 = floorf(i1);
        ba[d] = (int)f0;  wa[d] = i0 - f0;
        bb[d] = (int)f1;  wb[d] = i1 - f1;
    }
    float ta = (1.f - wa[2]) * (1.f - wa[3]) * (1.f - wa[4]);
    float tb = (1.f - wb[2]) * (1.f - wb[3]) * (1.f - wb[4]);
    int la = (ba[2] * 256 + ba[3] * 16 + ba[4]) * 256 + ba[0] * 16 + ba[1];
    int lb = (bb[2] * 256 + bb[3] * 16 + bb[4]) * 256 + bb[0] * 16 + bb[1];
    int l0 = min(max(la, 0), PCELLS - 18);
    int l1 = min(max(lb, 0), PCELLS - 18);

    const int h = j >> 2;                  // d1-corner this lane holds
    float f10 = h ? wa[1] : 1.f - wa[1];
    float cA0 = (1.f - wa[0]) * ta * f10;  // d0 bottom
    float cB0 = wa[0] * ta * f10;          // d0+1
    float f11 = h ? wb[1] : 1.f - wb[1];
    float cA1 = (1.f - wb[0]) * tb * f11;
    float cB1 = wb[0] * tb * f11;

    // --- gathers ------------------------------------------------------------
    const char* gb = (const char*)gt;
    const size_t off = (size_t)16 * j;
    f32x4 vA0 = *(const f32x4*)(gb + (size_t)l0 * 64 + off);         // (l, l+1)
    f32x4 vB0 = *(const f32x4*)(gb + (size_t)(l0 + 16) * 64 + off);  // (l+16, l+17)
    f32x4 vA1 = *(const f32x4*)(gb + (size_t)l1 * 64 + off);
    f32x4 vB1 = *(const f32x4*)(gb + (size_t)(l1 + 16) * 64 + off);

    // --- accumulate ---------------------------------------------------------
    float acc0[8], acc1[8];
    const __half2* hA0 = (const __half2*)&vA0;
    const __half2* hB0 = (const __half2*)&vB0;
    const __half2* hA1 = (const __half2*)&vA1;
    const __half2* hB1 = (const __half2*)&vB1;
#pragma unroll
    for (int k = 0; k < 4; ++k) {
        float2 a0 = __half22float2(hA0[k]);
        float2 b0 = __half22float2(hB0[k]);
        acc0[2 * k]     = cA0 * a0.x + cB0 * b0.x;
        acc0[2 * k + 1] = cA0 * a0.y + cB0 * b0.y;
        float2 a1 = __half22float2(hA1[k]);
        float2 b1 = __half22float2(hB1[k]);
        acc1[2 * k]     = cA1 * a1.x + cB1 * b1.x;
        acc1[2 * k + 1] = cA1 * a1.y + cB1 * b1.y;
    }
    // combine the two d1 corners (lanes j and j^4 hold the same channel octet)
#pragma unroll
    for (int k = 0; k < 8; ++k) {
        acc0[k] += swz_xor4(acc0[k]);
        acc1[k] += swz_xor4(acc1[k]);
    }

    const int qo = j & 3;
    f32x4 lo0 = *(f32x4*)&acc0[0], hi0 = *(f32x4*)&acc0[4];
    f32x4 st0 = h ? hi0 : lo0;
    __builtin_nontemporal_store(
        st0, (f32x4*)(out + (size_t)n0 * CCH + 8 * qo + 4 * h));
    if (has1) {
        f32x4 lo1 = *(f32x4*)&acc1[0], hi1 = *(f32x4*)&acc1[4];
        f32x4 st1 = h ? hi1 : lo1;
        __builtin_nontemporal_store(
            st1, (f32x4*)(out + (size_t)n1 * CCH + 8 * qo + 4 * h));
    }
}

// ---------------------------------------------------------------------------
// Fallback: direct gather from native (C,P) f32 layout (workspace too small).
// ---------------------------------------------------------------------------
__device__ __forceinline__ void ray_corners_orig(
        const float* __restrict__ ray, const float* __restrict__ mn,
        const float* __restrict__ mx, int n, int* lin, float* wt) {
    float w[5]; int b[5];
#pragma unroll
    for (int d = 0; d < 5; ++d) {
        float m   = mn[d];
        float inv = __builtin_amdgcn_rcpf(mx[d] - m) * 15.0f;
        float i0  = (ray[(size_t)n * 5 + d] - m) * inv;
        float f0  = floorf(i0);
        b[d] = (int)f0;  w[d] = i0 - f0;
    }
    float tau = (1.f - w[2]) * (1.f - w[3]) * (1.f - w[4]);
    int rest  = b[2] * 256 + b[3] * 16 + b[4];
    wt[0] = (1.f - w[0]) * (1.f - w[1]) * tau;
    wt[1] = w[0] * (1.f - w[1]) * tau;
    wt[2] = (1.f - w[0]) * w[1] * tau;
    wt[3] = w[0] * w[1] * tau;
    int l00 = b[0] * 65536 + b[1] * 4096 + rest;
    int lv[4] = { l00, l00 + 65536, l00 + 4096, l00 + 65536 + 4096 };
#pragma unroll
    for (int f = 0; f < 4; ++f)
        lin[f] = min(max(lv[f], 0), PCELLS - 1);
}

__global__ __launch_bounds__(256) void direct_kernel(
        const float* __restrict__ ray, const float* __restrict__ g,
        const float* __restrict__ mn, const float* __restrict__ mx,
        float* __restrict__ out, int N) {
    int tid = blockIdx.x * blockDim.x + threadIdx.x;
    int n = tid >> 5;
    int c = tid & 31;
    if (n >= N) return;
    int lin[4]; float wt[4];
    ray_corners_orig(ray, mn, mx, n, lin, wt);
    const float* gc = g + (size_t)c * PCELLS;
    float acc = wt[0] * gc[lin[0]] + wt[1] * gc[lin[1]] +
                wt[2] * gc[lin[2]] + wt[3] * gc[lin[3]];
    out[(size_t)n * CCH + c] = acc;
}

extern "C" void kernel_launch(void* const* d_in, const int* in_sizes, int n_in,
                              void* d_out, int out_size, void* d_ws, size_t ws_size,
                              hipStream_t stream) {
    const float* ray  = (const float*)d_in[0];
    const float* grid = (const float*)d_in[1];
    const float* mn   = (const float*)d_in[2];
    const float* mx   = (const float*)d_in[3];
    float* out = (float*)d_out;
    const int N = in_sizes[0] / 5;

    const size_t gt_bytes = (size_t)PCELLS * CCH * sizeof(__half);   // 64 MiB

    if (ws_size >= gt_bytes) {
        __half* gt = (__half*)d_ws;
        transpose_kernel<<<2048, 256, 0, stream>>>(grid, gt);

        long long waves   = ((long long)N + 15) / 16;   // 16 rays per wave
        long long threads = waves * 64;
        fused_gather<<<(int)((threads + 255) / 256), 256, 0, stream>>>(
            ray, gt, mn, mx, out, N);
    } else {
        long long total = (long long)N * CCH;
        direct_kernel<<<(int)((total + 255) / 256), 256, 0, stream>>>(
            ray, grid, mn, mx, out, N);
    }
}